// Round 9
// baseline (243.738 us; speedup 1.0000x reference)
//
#include <hip/hip_runtime.h>

// ---------------------------------------------------------------------------
// SelfAttention: B=4, S=2048, D=1024, fp32 in/out, causal, no 1/sqrt(d).
// fp16 MFMA (16x16x32), fp32 accumulate, fp32 softmax.
// R9 = R8 + (a) NST template: stages per barrier. QKV keeps NST=2 (BK=64,
// 32KB LDS, 3 blocks/CU). Scores/PV use NST=4 (BK=128, 64KB LDS): their
// grids are only ~2 blocks/CU, so the 2-block LDS cap is free and barrier
// drains halve again. (b) softmax rewritten wave-per-row (4 rows/block,
// butterfly shuffles, no LDS/barriers).
//
// ws layout (MiB):
//   [0,32)    Q,K fp16 slabs; later P fp16 overlays (after scores read Q,K)
//   [32,48)   Vt fp16 (b,e,s) — written by QKV epilogue
//   [48,112)  S fp32 (4x2048x2048)
//   [48,64)   x_h fp16      (over S; dead before S written)
//   [64,70)   Wh  fp16 [3072,1024] (over S; dead before S written)
// ---------------------------------------------------------------------------

typedef _Float16 h8 __attribute__((ext_vector_type(8)));
typedef _Float16 h4 __attribute__((ext_vector_type(4)));
typedef float f32x4 __attribute__((ext_vector_type(4)));

#define BM 128
#define BN 128

__device__ __forceinline__ void gl_lds16(const _Float16* g, _Float16* l) {
    __builtin_amdgcn_global_load_lds(
        (const __attribute__((address_space(1))) void*)g,
        (__attribute__((address_space(3))) void*)l, 16, 0, 0);
}

// NT GEMM: C[m][n] = sum_k A[m][k]*B[n][k]; A,B fp16 row-major, stride K.
// SWZ: 1 = QKV residue (grid.x=1536), 2 = scores balanced triangle (136),
//      3 = PV residue (128). OM: 0 = fp32 C (ldc=N, +z*sCz), 2 = QKV slab
//      store (Q,K row-major; V transposed to (b,e,s)). KLIM: clip K at m0+BM.
// NST: BK=32*NST staged as NST 8KB sub-buffers per barrier.
template<int SWZ, int OM, bool KLIM, int NST>
__global__ __launch_bounds__(256) void gemm_nt(
    const _Float16* __restrict__ A, const _Float16* __restrict__ B,
    void* __restrict__ Cp, int N, int K,
    size_t sAz, size_t sBz, size_t sCz)
{
    __shared__ __align__(16) char smem[NST * 16384];
    _Float16* As = (_Float16*)smem;                     // NST x 4096 halves
    _Float16* Bs = (_Float16*)(smem + NST * 8192);      // NST x 4096 halves

    int bx, by;
    if (SWZ == 1) {
        const int r = blockIdx.x & 7, q2 = blockIdx.x >> 3;
        bx = q2 >> 3;
        by = ((q2 & 7) << 3) | r;
    } else if (SWZ == 2) {
        const int r = blockIdx.x & 7, g = blockIdx.x >> 3;   // g in 0..16
        if (g <= r) { by = r;      bx = g; }
        else        { by = 15 - r; bx = g - (r + 1); }
    } else {                                      // SWZ == 3
        const int r = blockIdx.x & 7, g = blockIdx.x >> 3;   // g in 0..15
        by = (g & 1) ? (15 - r) : r;
        bx = g >> 1;
    }

    const int tid  = threadIdx.x;
    const int lane = tid & 63;
    const int wv   = tid >> 6;
    const int m0 = by * BM, n0 = bx * BN;
    const size_t z = blockIdx.z;

    // staging (per 8KB stage): 8 chunks of 1KB; wave wv stages chunks {wv,wv+4};
    // lane l -> row 16c+(l>>2); XOR-swizzled source group gsrc=(l&3)^((l>>3)&3)
    // (LDS dst forced to c*1KB + l*16B; reads undo via sg = qd^((la>>1)&3)).
    // Stage s: +32*s halves folded into the GLOBAL pointer (imm offset would
    // shift the LDS address too).
    const int lr = lane >> 2;
    const int lc = ((lane & 3) ^ ((lane >> 3) & 3)) * 8;
    const _Float16* pA0 = A + z * sAz + (size_t)(m0 + wv * 16 + lr) * K + lc;
    const _Float16* pA1 = pA0 + (size_t)64 * K;
    const _Float16* pB0 = B + z * sBz + (size_t)(n0 + wv * 16 + lr) * K + lc;
    const _Float16* pB1 = pB0 + (size_t)64 * K;
    _Float16* lA0 = As + wv * 512;
    _Float16* lA1 = As + (wv + 4) * 512;
    _Float16* lB0 = Bs + wv * 512;
    _Float16* lB1 = Bs + (wv + 4) * 512;

    // MFMA geometry: 4 waves 2x2, each wave 64x64 = 4x4 frags of 16x16x32
    const int la = lane & 15;
    const int qd = lane >> 4;
    const int wm = (wv >> 1) * 64;
    const int wn = (wv & 1) * 64;
    const int sg = (qd ^ ((la >> 1) & 3)) * 8;   // swizzled k-group offset

    f32x4 acc[4][4];
    #pragma unroll
    for (int i = 0; i < 4; i++)
        #pragma unroll
        for (int j = 0; j < 4; j++)
            acc[i][j] = (f32x4){0.f, 0.f, 0.f, 0.f};

    const int kEnd = KLIM ? (m0 + BM) : K;

    for (int k0 = 0; k0 < kEnd; k0 += 32 * NST) {
        #pragma unroll
        for (int s = 0; s < NST; s++) {
            gl_lds16(pA0 + 32 * s, lA0 + 4096 * s);
            gl_lds16(pA1 + 32 * s, lA1 + 4096 * s);
            gl_lds16(pB0 + 32 * s, lB0 + 4096 * s);
            gl_lds16(pB1 + 32 * s, lB1 + 4096 * s);
        }
        pA0 += 32 * NST; pA1 += 32 * NST; pB0 += 32 * NST; pB1 += 32 * NST;
        __syncthreads();

        #pragma unroll
        for (int s = 0; s < NST; s++) {
            h8 af[4], bf[4];
            #pragma unroll
            for (int i = 0; i < 4; i++)
                af[i] = *(const h8*)&As[s * 4096 + (wm + i * 16 + la) * 32 + sg];
            #pragma unroll
            for (int i = 0; i < 4; i++)
                bf[i] = *(const h8*)&Bs[s * 4096 + (wn + i * 16 + la) * 32 + sg];
            #pragma unroll
            for (int i = 0; i < 4; i++)
                #pragma unroll
                for (int j = 0; j < 4; j++)
                    acc[i][j] = __builtin_amdgcn_mfma_f32_16x16x32_f16(af[i], bf[j], acc[i][j], 0, 0, 0);
        }
        __syncthreads();
    }

    // epilogue: D layout col=lane&15, row=qd*4+reg
    if (OM == 2) {
        _Float16* C = (_Float16*)Cp;
        if (n0 < 2048) {
            // Q/K slabs, row-major [s][e], within-slab ld 1024
            #pragma unroll
            for (int i = 0; i < 4; i++)
                #pragma unroll
                for (int j = 0; j < 4; j++) {
                    const int col  = n0 + wn + j * 16 + la;
                    const size_t base = (size_t)(col >> 10) * 8388608 + (col & 1023);
                    #pragma unroll
                    for (int rr = 0; rr < 4; rr++)
                        C[base + (size_t)(m0 + wm + i * 16 + qd * 4 + rr) * 1024] =
                            (_Float16)acc[i][j][rr];
                }
        } else {
            // V slab stored transposed: Vt (b, e, s) at slab 2; rr -> s contiguous
            _Float16* Vt = C + (size_t)2 * 8388608;
            #pragma unroll
            for (int i = 0; i < 4; i++) {
                const int m  = m0 + wm + i * 16 + qd * 4;
                const int b  = m >> 11;
                const int sl = m & 2047;
                _Float16* Vb = Vt + (size_t)b * 2097152 + sl;
                #pragma unroll
                for (int j = 0; j < 4; j++) {
                    const int e = n0 - 2048 + wn + j * 16 + la;
                    h4 vv = { (_Float16)acc[i][j][0], (_Float16)acc[i][j][1],
                              (_Float16)acc[i][j][2], (_Float16)acc[i][j][3] };
                    *(h4*)(Vb + (size_t)e * 2048) = vv;
                }
            }
        }
    } else {
        float* C = (float*)Cp + z * sCz;
        #pragma unroll
        for (int i = 0; i < 4; i++)
            #pragma unroll
            for (int j = 0; j < 4; j++)
                #pragma unroll
                for (int rr = 0; rr < 4; rr++)
                    C[(size_t)(m0 + wm + i * 16 + qd * 4 + rr) * N + (n0 + wn + j * 16 + la)] =
                        acc[i][j][rr];
    }
}

// fused fp32->fp16: blocks [0,4096) convert x (8M), [4096,5632) convert W (3x1M)
__global__ __launch_bounds__(256) void cvt_all(
    const float* __restrict__ x, const float* __restrict__ Wq,
    const float* __restrict__ Wk, const float* __restrict__ Wv,
    _Float16* __restrict__ x_h, _Float16* __restrict__ Wh)
{
    const int bid = blockIdx.x;
    const float* src; _Float16* dst; size_t off;
    if (bid < 4096) {
        src = x; dst = x_h; off = (size_t)bid * 2048;
    } else {
        const int b2 = bid - 4096;
        const int w = b2 >> 9;
        src = (w == 0) ? Wq : ((w == 1) ? Wk : Wv);
        dst = Wh + (size_t)w * 1048576;
        off = (size_t)(b2 & 511) * 2048;
    }
    const size_t i = off + (size_t)threadIdx.x * 8;
    float4 a = *(const float4*)(src + i);
    float4 b = *(const float4*)(src + i + 4);
    h8 o = { (_Float16)a.x, (_Float16)a.y, (_Float16)a.z, (_Float16)a.w,
             (_Float16)b.x, (_Float16)b.y, (_Float16)b.z, (_Float16)b.w };
    *(h8*)(dst + i) = o;
}

// causal row softmax, wave-per-row: block = 4 waves = 4 rows. Butterfly
// shuffle reductions only (no LDS/barriers). Reads only k<=q chunks; writes
// only k < 128-ceil(q+1) (PV's KLIM never reads beyond).
__global__ __launch_bounds__(256) void softmax_causal(const float* __restrict__ S,
                                                      _Float16* __restrict__ P)
{
    const int wv   = threadIdx.x >> 6;
    const int lane = threadIdx.x & 63;
    const int idx  = blockIdx.x * 4 + wv;    // 0..8191
    const int q    = idx & 2047;
    const float* Srow = S + (size_t)idx * 2048;
    _Float16* Prow = P + (size_t)idx * 2048;

    float v[32];
    float mx = -3.4e38f;
    #pragma unroll
    for (int c = 0; c < 4; c++) {
        if (c * 512 <= q) {                  // wave-uniform branch
            const int k0 = c * 512 + lane * 8;
            if (k0 <= q) {
                float4 a = *(const float4*)(Srow + k0);
                float4 b = *(const float4*)(Srow + k0 + 4);
                v[c*8+0]=a.x; v[c*8+1]=a.y; v[c*8+2]=a.z; v[c*8+3]=a.w;
                v[c*8+4]=b.x; v[c*8+5]=b.y; v[c*8+6]=b.z; v[c*8+7]=b.w;
                #pragma unroll
                for (int j = 0; j < 8; j++)
                    if (k0 + j <= q) mx = fmaxf(mx, v[c*8+j]);
            }
        }
    }
    #pragma unroll
    for (int o = 32; o > 0; o >>= 1) mx = fmaxf(mx, __shfl_xor(mx, o, 64));

    float sum = 0.f;
    #pragma unroll
    for (int c = 0; c < 4; c++) {
        if (c * 512 <= q) {
            const int k0 = c * 512 + lane * 8;
            #pragma unroll
            for (int j = 0; j < 8; j++) {
                float e = (k0 + j <= q) ? __expf(v[c*8+j] - mx) : 0.f;
                v[c*8+j] = e;
                sum += e;
            }
        }
    }
    #pragma unroll
    for (int o = 32; o > 0; o >>= 1) sum += __shfl_xor(sum, o, 64);
    const float inv = 1.f / sum;

    const int kceil = ((q >> 7) + 1) << 7;   // PV reads cols < kceil
    #pragma unroll
    for (int c = 0; c < 4; c++) {
        if (c * 512 < kceil) {               // implies c*512 <= q (both mult-128)
            const int k0 = c * 512 + lane * 8;
            if (k0 < kceil) {
                h8 o = { (_Float16)(v[c*8+0] * inv), (_Float16)(v[c*8+1] * inv),
                         (_Float16)(v[c*8+2] * inv), (_Float16)(v[c*8+3] * inv),
                         (_Float16)(v[c*8+4] * inv), (_Float16)(v[c*8+5] * inv),
                         (_Float16)(v[c*8+6] * inv), (_Float16)(v[c*8+7] * inv) };
                *(h8*)(Prow + k0) = o;
            }
        }
    }
}

extern "C" void kernel_launch(void* const* d_in, const int* in_sizes, int n_in,
                              void* d_out, int out_size, void* d_ws, size_t ws_size,
                              hipStream_t stream) {
    const float* x  = (const float*)d_in[0];
    const float* Wq = (const float*)d_in[1];
    const float* Wk = (const float*)d_in[2];
    const float* Wv = (const float*)d_in[3];
    float* out = (float*)d_out;

    const size_t MiB = 1024 * 1024;
    char* ws = (char*)d_ws;
    _Float16* QKVh = (_Float16*)ws;                     // Q,K slabs + Vt at slab 2
    _Float16* Vt   = QKVh + (size_t)2 * 8388608;        // [32,48) MiB, (b,e,s)
    float*    S    = (float*)(ws + 48 * MiB);           // 64 MiB
    _Float16* x_h  = (_Float16*)(ws + 48 * MiB);        // 16 MiB (over S)
    _Float16* Wh   = (_Float16*)(ws + 64 * MiB);        // 6 MiB  (over S)
    _Float16* P    = (_Float16*)ws;                     // 32 MiB (over Q,K)

    const dim3 blk(256);

    // 0) fp32 -> fp16 conversions (one dispatch)
    cvt_all<<<dim3(5632), blk, 0, stream>>>(x, Wq, Wk, Wv, x_h, Wh);

    // 1) QKV fused: M=8192, N=3072; Q,K row-major slabs, V written as Vt(b,e,s)
    //    NST=2 (BK=64, 32KB LDS) — needs 3 blocks/CU.
    gemm_nt<1, 2, false, 2><<<dim3(1536), blk, 0, stream>>>(
        x_h, Wh, QKVh, 3072, 1024, 0, 0, 0);

    // 2) scores: balanced lower-triangle decode, 136 tiles/batch.
    //    NST=4 (BK=128, 64KB LDS) — grid is ~2 blocks/CU, LDS cap free.
    gemm_nt<2, 0, false, 4><<<dim3(136, 1, 4), blk, 0, stream>>>(
        QKVh, QKVh + 8388608, S, 2048, 1024,
        (size_t)2097152, (size_t)2097152, (size_t)4194304);

    // 3) causal softmax rows -> P fp16 (over Q,K), wave-per-row
    softmax_causal<<<dim3(2048), blk, 0, stream>>>(S, P);

    // 4) out = P @ Vt^T, fp32 out, K clipped at m0+128, residue swizzle.
    //    NST=4 (BK=128) — grid exactly 2 blocks/CU.
    gemm_nt<3, 0, true, 4><<<dim3(128, 1, 4), blk, 0, stream>>>(
        P, Vt, out, 1024, 2048,
        (size_t)4194304, (size_t)2097152, (size_t)2097152);
}